// Round 7
// baseline (248.697 us; speedup 1.0000x reference)
//
#include <hip/hip_runtime.h>
#include <stdint.h>

#define NPAT 4096
#define DIM  256
#define EPSV 1e-8f
#define BT   128        // block tile (M and N); wave tile 64x64 (2x2 of 32x32x64 MX)
#define NT   (NPAT / BT)            // 32 tiles per dim
#define NBLK (NT * (NT + 1) / 2)    // 528 upper-triangle blocks
#define NSTEP 16        // K = 1024 fp8 bytes = 16 steps of 64
#define NBINS 4096

typedef float f32x4  __attribute__((ext_vector_type(4)));
typedef float f32x16 __attribute__((ext_vector_type(16)));
typedef int   i32x8  __attribute__((ext_vector_type(8)));

// ---- workspace layout (bytes) ----
// [0..256): scalars: f[0]=sim_sum, f[1]=cox n/d, u[2]=ticket
#define WS_DVAL_OFF 256                          // float4[NPAT]
#define WS_MVEC_OFF (WS_DVAL_OFF + 16*NPAT)      // float4[NPAT]
#define WS_XN_OFF   (WS_MVEC_OFF + 16*NPAT)      // fragment-ready blobs, 4 MB
// XnF blob layout: ((g*16 + s)*64 + lane)*32 ; g = patient>>5 (32-row group),
// s = K-step (64 fp8 each), lane = (k_half)*32 + (patient&31), 32 B/lane.

__device__ __forceinline__ float decode_margin(const int* pm) {
  int v = *pm;
  if (v > -16777216 && v < 16777216) return (float)v;  // stored as int
  return __int_as_float(v);                            // stored as float bits
}

// ---------- prep: normalize, quantize fp8, scatter into fragment-ready blobs ----------
__global__ __launch_bounds__(256) void prep_kernel(
    const float4* __restrict__ eb0, const float4* __restrict__ eb1,
    const float4* __restrict__ eb2, const float4* __restrict__ eb3,
    uint8_t* __restrict__ XnF, float* __restrict__ dval_f,
    float* __restrict__ mvec_f, float* __restrict__ scal)
{
  const int i    = blockIdx.x;
  const int wv   = threadIdx.x >> 6;   // modality
  const int lane = threadIdx.x & 63;
  const float4* ebs[4] = {eb0, eb1, eb2, eb3};
  const float4 v = ebs[wv][i * (DIM / 4) + lane];
  float s = v.x * v.x + v.y * v.y + v.z * v.z + v.w * v.w;
#pragma unroll
  for (int o = 32; o; o >>= 1) s += __shfl_down(s, o, 64);
  s = __shfl(s, 0, 64);
  const float x0 = __shfl(v.x, 0, 64);
  const bool eq = (v.x == x0) && (v.y == x0) && (v.z == x0) && (v.w == x0);
  const bool miss = (__ballot(eq) == ~0ull);
  const float nrm = sqrtf(s);
  const float den = fmaxf(nrm, EPSV);
  const float inv = miss ? 0.0f : (1.0f / den);
  int p = 0;
  p = __builtin_amdgcn_cvt_pk_fp8_f32(v.x * inv, v.y * inv, p, false);
  p = __builtin_amdgcn_cvt_pk_fp8_f32(v.z * inv, v.w * inv, p, true);
  // fragment-ready scatter: kk = wv*256 + lane*4
  const int g  = i >> 5, r = i & 31;
  const int ss = wv * 4 + (lane >> 4);
  const int h  = (lane >> 3) & 1;
  const int b  = (lane & 7) * 4;
  *(int*)&XnF[(size_t)((g * 16 + ss) * 64 + (h * 32 + r)) * 32 + b] = p;
  if (lane == 0) {
    const float diag = (nrm * nrm) / (den * den);
    dval_f[i * 4 + wv] = miss ? 0.0f : diag;
    mvec_f[i * 4 + wv] = miss ? 0.0f : 1.0f;
  }
  if (i == 0 && threadIdx.x == 0) {
    scal[0] = 0.0f;                    // sim accumulator
    scal[1] = 0.0f;                    // cox n/d
    ((unsigned*)scal)[2] = 0u;         // ticket
  }
}

// ---------- fused: cox (block 0) + sim GEMM (blocks 1..NBLK) + finalize ----------
__global__ __launch_bounds__(256, 3) void sim_gemm_kernel(
    const uint8_t* __restrict__ XnF, const float4* __restrict__ dval,
    const float4* __restrict__ mvec, const int* __restrict__ pmargin,
    const float* __restrict__ h, const int* __restrict__ t,
    const int* __restrict__ e, float* __restrict__ scal,
    float* __restrict__ out)
{
  __shared__ __align__(16) uint8_t smem[16384 + 256];
  const int L   = blockIdx.x;
  const int tid = threadIdx.x;
  const int lane = tid & 63, wvv = tid >> 6;

  if (L == 0) {
    // ================= Cox path (256 threads) =================
    float* bins = (float*)smem;                      // 16 KB
    float* wt   = (float*)(smem + 16384);            // 4 floats
    float* rn   = (float*)(smem + 16384 + 32);
    float* rd   = (float*)(smem + 16384 + 64);
#pragma unroll
    for (int k = 0; k < 16; ++k) bins[tid + k * 256] = 0.0f;
    __syncthreads();
#pragma unroll
    for (int k = 0; k < 16; ++k) {
      const int i = tid + k * 256;
      atomicAdd(&bins[t[i]], expf(h[i]));
    }
    __syncthreads();
    // suffix scan: bins[b] <- sum_{v>=b} bins[v]; thread owns bins[16t..16t+15]
    float seg[16]; float part = 0.0f;
#pragma unroll
    for (int k = 0; k < 16; ++k) { seg[k] = bins[tid * 16 + k]; part += seg[k]; }
    float sfx = part;                                // inclusive suffix within wave
#pragma unroll
    for (int off = 1; off < 64; off <<= 1) {
      const float u = __shfl_down(sfx, off, 64);
      if (lane + off < 64) sfx += u;
    }
    if (lane == 0) wt[wvv] = sfx;                    // wave totals
    __syncthreads();
    float above = 0.0f;
    for (int w = wvv + 1; w < 4; ++w) above += wt[w];
    float run = above + (sfx - part);                // strictly-after my segment
#pragma unroll
    for (int k = 15; k >= 0; --k) { run += seg[k]; bins[tid * 16 + k] = run; }
    __syncthreads();
    float nloc = 0.0f, dloc = 0.0f;
#pragma unroll
    for (int k = 0; k < 16; ++k) {
      const int i = tid + k * 256;
      const float ei = (float)e[i];
      if (ei != 0.0f) { nloc += ei * (h[i] - logf(bins[t[i]])); dloc += ei; }
    }
#pragma unroll
    for (int o = 32; o; o >>= 1) {
      nloc += __shfl_down(nloc, o, 64);
      dloc += __shfl_down(dloc, o, 64);
    }
    if (lane == 0) { rn[wvv] = nloc; rd[wvv] = dloc; }
    __syncthreads();
    if (tid == 0) {
      float n = 0.0f, d = 0.0f;
#pragma unroll
      for (int k = 0; k < 4; ++k) { n += rn[k]; d += rd[k]; }
      atomicExch(&scal[1], n / d);                   // publish cox
      __threadfence();
      const unsigned old = atomicAdd(&((unsigned*)scal)[2], 1u);
      if (old == NBLK) {                             // last of NBLK+1 blocks
        __threadfence();
        out[0] = atomicAdd(&scal[0], 0.0f) - (n / d);
      }
    }
    return;
  }

  // ================= GEMM path =================
  const int T = L - 1;
  int bi = (int)((2 * NT + 1 - sqrtf((float)((2 * NT + 1) * (2 * NT + 1)) - 8.0f * T)) * 0.5f);
  if (bi < 0) bi = 0;
  if (bi > NT - 1) bi = NT - 1;
  while (bi > 0 && bi * NT - bi * (bi - 1) / 2 > T) --bi;
  while ((bi + 1) * NT - (bi + 1) * bi / 2 <= T) ++bi;
  const int bj = bi + (T - (bi * NT - bi * (bi - 1) / 2));

  const int wi = wvv >> 1, wj = wvv & 1;        // wave tile 64x64 within 128x128
  const int gA0 = bi * 4 + wi * 2;              // 32-row groups
  const int gB0 = bj * 4 + wj * 2;
  const uint8_t* pA = XnF + (size_t)(gA0 * 16) * 2048 + lane * 32;
  const uint8_t* pB = XnF + (size_t)(gB0 * 16) * 2048 + lane * 32;

  f32x16 acc[2][2] = {};
  i32x8 af[2][2], bf[2][2];

#define LOADSTEP(buf, s)                                              \
  do {                                                                \
    af[buf][0] = *(const i32x8*)(pA + (size_t)(s) * 2048);            \
    af[buf][1] = *(const i32x8*)(pA + 32768 + (size_t)(s) * 2048);    \
    bf[buf][0] = *(const i32x8*)(pB + (size_t)(s) * 2048);            \
    bf[buf][1] = *(const i32x8*)(pB + 32768 + (size_t)(s) * 2048);    \
  } while (0)

  LOADSTEP(0, 0);
#pragma unroll
  for (int s = 0; s < NSTEP; ++s) {
    const int c = s & 1;
    if (s < NSTEP - 1) LOADSTEP(c ^ 1, s + 1);
#pragma unroll
    for (int mi = 0; mi < 2; ++mi)
#pragma unroll
      for (int mj = 0; mj < 2; ++mj)
        acc[mi][mj] = __builtin_amdgcn_mfma_scale_f32_32x32x64_f8f6f4(
            af[c][mi], bf[c][mj], acc[mi][mj],
            0, 0,                         // cbsz=fp8(e4m3), blgp=fp8(e4m3)
            0, 0x7F7F7F7F,                // A scale: unit E8M0 in every byte
            0, 0x7F7F7F7F);               // B scale: unit
  }
#undef LOADSTEP

  // epilogue: stage dval/mvec for both tiles in LDS (8 KB)
  float4* eRDi = (float4*)smem;
  float4* eCMi = (float4*)smem + BT;
  float4* eRDj = (float4*)smem + 2 * BT;
  float4* eCMj = (float4*)smem + 3 * BT;
  float*  wred = (float*)(smem + 8192);
  if (tid < BT) {
    eRDi[tid] = dval[bi * BT + tid];
    eCMi[tid] = mvec[bi * BT + tid];
  } else {
    const int ss = tid - BT;
    eRDj[ss] = dval[bj * BT + ss];
    eCMj[ss] = mvec[bj * BT + ss];
  }
  __syncthreads();

  const float margin = decode_margin(pmargin);
  const bool isDiag = (bi == bj);
  float local = 0.0f;
  const int colA = lane & 31, hsel = lane >> 5;  // C/D: col=lane&31, row=(reg&3)+8*(reg>>2)+4*(lane>>5)
#pragma unroll
  for (int mi = 0; mi < 2; ++mi) {
#pragma unroll
    for (int mj = 0; mj < 2; ++mj) {
      const int jl = wj * 64 + mj * 32 + colA;
      const float4 cmj = eCMj[jl];
      const float4 rdj = eRDj[jl];
#pragma unroll
      for (int rr = 0; rr < 16; ++rr) {
        const int il = wi * 64 + mi * 32 + (rr & 3) + 8 * (rr >> 2) + 4 * hsel;
        const float4 rdi = eRDi[il];
        const float sv = acc[mi][mj][rr];
        const float own_ij = rdi.x * cmj.x + rdi.y * cmj.y + rdi.z * cmj.z + rdi.w * cmj.w;
        const float v1 = fmaxf(margin - sv + own_ij, 0.0f);
        local += (isDiag && il == jl) ? 0.0f : v1;
        if (!isDiag) {                          // transposed pair (j,i)
          const float4 cmi = eCMi[il];
          const float own_ji = rdj.x * cmi.x + rdj.y * cmi.y + rdj.z * cmi.z + rdj.w * cmi.w;
          local += fmaxf(margin - sv + own_ji, 0.0f);
        }
      }
    }
  }
#pragma unroll
  for (int o = 32; o; o >>= 1) local += __shfl_down(local, o, 64);
  if (lane == 0) wred[wvv] = local;
  __syncthreads();
  if (tid == 0) {
    atomicAdd(&scal[0], wred[0] + wred[1] + wred[2] + wred[3]);
    __threadfence();
    const unsigned old = atomicAdd(&((unsigned*)scal)[2], 1u);
    if (old == NBLK) {                          // last of NBLK+1 blocks
      __threadfence();
      out[0] = atomicAdd(&scal[0], 0.0f) - atomicAdd(&scal[1], 0.0f);
    }
  }
}

extern "C" void kernel_launch(void* const* d_in, const int* in_sizes, int n_in,
                              void* d_out, int out_size, void* d_ws, size_t ws_size,
                              hipStream_t stream) {
  const float* h    = (const float*)d_in[0];
  const int*   t    = (const int*)  d_in[1];
  const int*   e    = (const int*)  d_in[2];
  const float4* eb0 = (const float4*)d_in[3];
  const float4* eb1 = (const float4*)d_in[4];
  const float4* eb2 = (const float4*)d_in[5];
  const float4* eb3 = (const float4*)d_in[6];
  const int*   pm   = (const int*)  d_in[7];

  char*    ws   = (char*)d_ws;
  float*   scal = (float*)ws;
  float*   dvf  = (float*)(ws + WS_DVAL_OFF);
  float*   mvf  = (float*)(ws + WS_MVEC_OFF);
  uint8_t* XnF  = (uint8_t*)(ws + WS_XN_OFF);

  prep_kernel<<<NPAT, 256, 0, stream>>>(eb0, eb1, eb2, eb3, XnF, dvf, mvf, scal);
  sim_gemm_kernel<<<NBLK + 1, 256, 0, stream>>>(XnF, (const float4*)dvf, (const float4*)mvf,
                                                pm, h, t, e, scal, (float*)d_out);
}

// Round 8
// 109.012 us; speedup vs baseline: 2.2814x; 2.2814x over previous
//
#include <hip/hip_runtime.h>
#include <stdint.h>

#define NPAT 4096
#define DIM  256
#define EPSV 1e-8f
#define BT   128        // block tile (M and N); wave tile 64x64 (2x2 of 32x32x64 MX)
#define NT   (NPAT / BT)            // 32 tiles per dim
#define NBLK (NT * (NT + 1) / 2)    // 528 upper-triangle blocks
#define NSTEP 16        // K = 1024 fp8 bytes = 16 steps of 64
#define NBINS 4096

typedef float f32x4  __attribute__((ext_vector_type(4)));
typedef float f32x16 __attribute__((ext_vector_type(16)));
typedef int   i32x8  __attribute__((ext_vector_type(8)));

// ---- workspace layout (bytes) ----
// [0..256): scalars: f[0]=sim_sum, f[1]=cox n/d, u[2]=ticket
#define WS_DVAL_OFF 256                          // float4[NPAT]
#define WS_MVEC_OFF (WS_DVAL_OFF + 16*NPAT)      // float4[NPAT]
#define WS_XN_OFF   (WS_MVEC_OFF + 16*NPAT)      // fragment-ready blobs, 4 MB
// XnF blob layout: ((g*16 + s)*64 + lane)*32 ; g = patient>>5 (32-row group),
// s = K-step (64 fp8 each), lane = (k_half)*32 + (patient&31), 32 B/lane.

__device__ __forceinline__ float decode_margin(const int* pm) {
  int v = *pm;
  if (v > -16777216 && v < 16777216) return (float)v;  // stored as int
  return __int_as_float(v);                            // stored as float bits
}

// ---------- prep: normalize, quantize fp8, scatter into fragment-ready blobs ----------
__global__ __launch_bounds__(256) void prep_kernel(
    const float4* __restrict__ eb0, const float4* __restrict__ eb1,
    const float4* __restrict__ eb2, const float4* __restrict__ eb3,
    uint8_t* __restrict__ XnF, float* __restrict__ dval_f,
    float* __restrict__ mvec_f, float* __restrict__ scal)
{
  const int i    = blockIdx.x;
  const int wv   = threadIdx.x >> 6;   // modality
  const int lane = threadIdx.x & 63;
  const float4* ebs[4] = {eb0, eb1, eb2, eb3};
  const float4 v = ebs[wv][i * (DIM / 4) + lane];
  float s = v.x * v.x + v.y * v.y + v.z * v.z + v.w * v.w;
#pragma unroll
  for (int o = 32; o; o >>= 1) s += __shfl_down(s, o, 64);
  s = __shfl(s, 0, 64);
  const float x0 = __shfl(v.x, 0, 64);
  const bool eq = (v.x == x0) && (v.y == x0) && (v.z == x0) && (v.w == x0);
  const bool miss = (__ballot(eq) == ~0ull);
  const float nrm = sqrtf(s);
  const float den = fmaxf(nrm, EPSV);
  const float inv = miss ? 0.0f : (1.0f / den);
  int p = 0;
  p = __builtin_amdgcn_cvt_pk_fp8_f32(v.x * inv, v.y * inv, p, false);
  p = __builtin_amdgcn_cvt_pk_fp8_f32(v.z * inv, v.w * inv, p, true);
  // fragment-ready scatter: kk = wv*256 + lane*4
  const int g  = i >> 5, r = i & 31;
  const int ss = wv * 4 + (lane >> 4);
  const int h  = (lane >> 3) & 1;
  const int b  = (lane & 7) * 4;
  *(int*)&XnF[(size_t)((g * 16 + ss) * 64 + (h * 32 + r)) * 32 + b] = p;
  if (lane == 0) {
    const float diag = (nrm * nrm) / (den * den);
    dval_f[i * 4 + wv] = miss ? 0.0f : diag;
    mvec_f[i * 4 + wv] = miss ? 0.0f : 1.0f;
  }
  if (i == 0 && threadIdx.x == 0) {
    scal[0] = 0.0f;                    // sim accumulator
    scal[1] = 0.0f;                    // cox n/d
    ((unsigned*)scal)[2] = 0u;         // ticket
  }
}

// ---------- fused: cox (block 0) + sim GEMM (blocks 1..NBLK) + finalize ----------
__global__ __launch_bounds__(256, 3) void sim_gemm_kernel(
    const uint8_t* __restrict__ XnF, const float4* __restrict__ dval,
    const float4* __restrict__ mvec, const int* __restrict__ pmargin,
    const float* __restrict__ h, const int* __restrict__ t,
    const int* __restrict__ e, float* __restrict__ scal,
    float* __restrict__ out)
{
  __shared__ __align__(16) uint8_t smem[16384 + 256];
  const int L   = blockIdx.x;
  const int tid = threadIdx.x;
  const int lane = tid & 63, wvv = tid >> 6;

  if (L == 0) {
    // ================= Cox path (256 threads) =================
    float* bins = (float*)smem;                      // 16 KB
    float* wt   = (float*)(smem + 16384);            // 4 floats
    float* rn   = (float*)(smem + 16384 + 32);
    float* rd   = (float*)(smem + 16384 + 64);
#pragma unroll
    for (int k = 0; k < 16; ++k) bins[tid + k * 256] = 0.0f;
    __syncthreads();
#pragma unroll
    for (int k = 0; k < 16; ++k) {
      const int i = tid + k * 256;
      atomicAdd(&bins[t[i]], expf(h[i]));
    }
    __syncthreads();
    // suffix scan: bins[b] <- sum_{v>=b} bins[v]; thread owns bins[16t..16t+15]
    float seg[16]; float part = 0.0f;
#pragma unroll
    for (int k = 0; k < 16; ++k) { seg[k] = bins[tid * 16 + k]; part += seg[k]; }
    float sfx = part;                                // inclusive suffix within wave
#pragma unroll
    for (int off = 1; off < 64; off <<= 1) {
      const float u = __shfl_down(sfx, off, 64);
      if (lane + off < 64) sfx += u;
    }
    if (lane == 0) wt[wvv] = sfx;                    // wave totals
    __syncthreads();
    float above = 0.0f;
    for (int w = wvv + 1; w < 4; ++w) above += wt[w];
    float run = above + (sfx - part);                // strictly-after my segment
#pragma unroll
    for (int k = 15; k >= 0; --k) { run += seg[k]; bins[tid * 16 + k] = run; }
    __syncthreads();
    float nloc = 0.0f, dloc = 0.0f;
#pragma unroll
    for (int k = 0; k < 16; ++k) {
      const int i = tid + k * 256;
      const float ei = (float)e[i];
      if (ei != 0.0f) { nloc += ei * (h[i] - logf(bins[t[i]])); dloc += ei; }
    }
#pragma unroll
    for (int o = 32; o; o >>= 1) {
      nloc += __shfl_down(nloc, o, 64);
      dloc += __shfl_down(dloc, o, 64);
    }
    if (lane == 0) { rn[wvv] = nloc; rd[wvv] = dloc; }
    __syncthreads();
    if (tid == 0) {
      float n = 0.0f, d = 0.0f;
#pragma unroll
      for (int k = 0; k < 4; ++k) { n += rn[k]; d += rd[k]; }
      atomicExch(&scal[1], n / d);                   // publish cox
      __threadfence();
      const unsigned old = atomicAdd(&((unsigned*)scal)[2], 1u);
      if (old == NBLK) {                             // last of NBLK+1 blocks
        __threadfence();
        out[0] = atomicAdd(&scal[0], 0.0f) - (n / d);
      }
    }
    return;
  }

  // ================= GEMM path =================
  const int T = L - 1;
  int bi = (int)((2 * NT + 1 - sqrtf((float)((2 * NT + 1) * (2 * NT + 1)) - 8.0f * T)) * 0.5f);
  if (bi < 0) bi = 0;
  if (bi > NT - 1) bi = NT - 1;
  while (bi > 0 && bi * NT - bi * (bi - 1) / 2 > T) --bi;
  while ((bi + 1) * NT - (bi + 1) * bi / 2 <= T) ++bi;
  const int bj = bi + (T - (bi * NT - bi * (bi - 1) / 2));

  const int wi = wvv >> 1, wj = wvv & 1;        // wave tile 64x64 within 128x128
  const int gA0 = bi * 4 + wi * 2;              // 32-row groups
  const int gB0 = bj * 4 + wj * 2;
  const uint8_t* pA = XnF + (size_t)(gA0 * 16) * 2048 + lane * 32;
  const uint8_t* pB = XnF + (size_t)(gB0 * 16) * 2048 + lane * 32;

  f32x16 acc[2][2] = {};

  // single-buffered operands; unroll 2 bounds live registers (~140 total)
#pragma unroll 2
  for (int s = 0; s < NSTEP; ++s) {
    const i32x8 a0 = *(const i32x8*)(pA + (size_t)s * 2048);
    const i32x8 a1 = *(const i32x8*)(pA + 32768 + (size_t)s * 2048);
    const i32x8 b0 = *(const i32x8*)(pB + (size_t)s * 2048);
    const i32x8 b1 = *(const i32x8*)(pB + 32768 + (size_t)s * 2048);
    acc[0][0] = __builtin_amdgcn_mfma_scale_f32_32x32x64_f8f6f4(
        a0, b0, acc[0][0], 0, 0, 0, 0x7F7F7F7F, 0, 0x7F7F7F7F);
    acc[0][1] = __builtin_amdgcn_mfma_scale_f32_32x32x64_f8f6f4(
        a0, b1, acc[0][1], 0, 0, 0, 0x7F7F7F7F, 0, 0x7F7F7F7F);
    acc[1][0] = __builtin_amdgcn_mfma_scale_f32_32x32x64_f8f6f4(
        a1, b0, acc[1][0], 0, 0, 0, 0x7F7F7F7F, 0, 0x7F7F7F7F);
    acc[1][1] = __builtin_amdgcn_mfma_scale_f32_32x32x64_f8f6f4(
        a1, b1, acc[1][1], 0, 0, 0, 0x7F7F7F7F, 0, 0x7F7F7F7F);
  }

  // epilogue: stage dval/mvec for both tiles in LDS (8 KB)
  float4* eRDi = (float4*)smem;
  float4* eCMi = (float4*)smem + BT;
  float4* eRDj = (float4*)smem + 2 * BT;
  float4* eCMj = (float4*)smem + 3 * BT;
  float*  wred = (float*)(smem + 8192);
  if (tid < BT) {
    eRDi[tid] = dval[bi * BT + tid];
    eCMi[tid] = mvec[bi * BT + tid];
  } else {
    const int ss = tid - BT;
    eRDj[ss] = dval[bj * BT + ss];
    eCMj[ss] = mvec[bj * BT + ss];
  }
  __syncthreads();

  const float margin = decode_margin(pmargin);
  const bool isDiag = (bi == bj);
  float local = 0.0f;
  const int colA = lane & 31, hsel = lane >> 5;  // C/D: col=lane&31, row=(reg&3)+8*(reg>>2)+4*(lane>>5)
#pragma unroll
  for (int mi = 0; mi < 2; ++mi) {
#pragma unroll
    for (int mj = 0; mj < 2; ++mj) {
      const int jl = wj * 64 + mj * 32 + colA;
      const float4 cmj = eCMj[jl];
      const float4 rdj = eRDj[jl];
#pragma unroll
      for (int rr = 0; rr < 16; ++rr) {
        const int il = wi * 64 + mi * 32 + (rr & 3) + 8 * (rr >> 2) + 4 * hsel;
        const float4 rdi = eRDi[il];
        const float sv = acc[mi][mj][rr];
        const float own_ij = rdi.x * cmj.x + rdi.y * cmj.y + rdi.z * cmj.z + rdi.w * cmj.w;
        const float v1 = fmaxf(margin - sv + own_ij, 0.0f);
        local += (isDiag && il == jl) ? 0.0f : v1;
        if (!isDiag) {                          // transposed pair (j,i)
          const float4 cmi = eCMi[il];
          const float own_ji = rdj.x * cmi.x + rdj.y * cmi.y + rdj.z * cmi.z + rdj.w * cmi.w;
          local += fmaxf(margin - sv + own_ji, 0.0f);
        }
      }
    }
  }
#pragma unroll
  for (int o = 32; o; o >>= 1) local += __shfl_down(local, o, 64);
  if (lane == 0) wred[wvv] = local;
  __syncthreads();
  if (tid == 0) {
    atomicAdd(&scal[0], wred[0] + wred[1] + wred[2] + wred[3]);
    __threadfence();
    const unsigned old = atomicAdd(&((unsigned*)scal)[2], 1u);
    if (old == NBLK) {                          // last of NBLK+1 blocks
      __threadfence();
      out[0] = atomicAdd(&scal[0], 0.0f) - atomicAdd(&scal[1], 0.0f);
    }
  }
}

extern "C" void kernel_launch(void* const* d_in, const int* in_sizes, int n_in,
                              void* d_out, int out_size, void* d_ws, size_t ws_size,
                              hipStream_t stream) {
  const float* h    = (const float*)d_in[0];
  const int*   t    = (const int*)  d_in[1];
  const int*   e    = (const int*)  d_in[2];
  const float4* eb0 = (const float4*)d_in[3];
  const float4* eb1 = (const float4*)d_in[4];
  const float4* eb2 = (const float4*)d_in[5];
  const float4* eb3 = (const float4*)d_in[6];
  const int*   pm   = (const int*)  d_in[7];

  char*    ws   = (char*)d_ws;
  float*   scal = (float*)ws;
  float*   dvf  = (float*)(ws + WS_DVAL_OFF);
  float*   mvf  = (float*)(ws + WS_MVEC_OFF);
  uint8_t* XnF  = (uint8_t*)(ws + WS_XN_OFF);

  prep_kernel<<<NPAT, 256, 0, stream>>>(eb0, eb1, eb2, eb3, XnF, dvf, mvf, scal);
  sim_gemm_kernel<<<NBLK + 1, 256, 0, stream>>>(XnF, (const float4*)dvf, (const float4*)mvf,
                                                pm, h, t, e, scal, (float*)d_out);
}